// Round 1
// baseline (3172.457 us; speedup 1.0000x reference)
//
#include <hip/hip_runtime.h>

#define B_  128
#define T_  4096
#define F_  64
#define H_  128
#define G4  512   // 4*H

typedef _Float16 half2_t __attribute__((ext_vector_type(2)));

#if __has_builtin(__builtin_amdgcn_fdot2)
__device__ __forceinline__ float fdot2(half2_t a, half2_t b, float c) {
  return __builtin_amdgcn_fdot2(a, b, c, false);
}
#else
__device__ __forceinline__ float fdot2(half2_t a, half2_t b, float c) {
  return c + (float)a[0] * (float)b[0] + (float)a[1] * (float)b[1];
}
#endif

__device__ __forceinline__ half2_t pack2(float a, float b) {
  half2_t r; r[0] = (_Float16)a; r[1] = (_Float16)b; return r;
}

// sigmoid(x) = 1/(1+2^(-x*log2e)) ; tanh(x) = 1 - 2/(2^(2x*log2e)+1)
__device__ __forceinline__ float fast_sigmoid(float x) {
  float e = __builtin_amdgcn_exp2f(x * -1.4426950408889634f);
  return __builtin_amdgcn_rcpf(1.0f + e);
}
__device__ __forceinline__ float fast_tanh(float x) {
  float e = __builtin_amdgcn_exp2f(x * 2.8853900817779268f);
  return 1.0f - 2.0f * __builtin_amdgcn_rcpf(e + 1.0f);
}

__global__ __launch_bounds__(512, 2) void lstm_seq_kernel(
    const float* __restrict__ X,    // [B, T, F]
    const float* __restrict__ Wih,  // [4H, F]
    const float* __restrict__ Whh,  // [4H, H]
    const float* __restrict__ bih,  // [4H]
    const float* __restrict__ bhh,  // [4H]
    float* __restrict__ out)        // [B, H]
{
  const int tid  = threadIdx.x;   // gate row j in [0, 512)
  const int b    = blockIdx.x;    // sequence
  const int lane = tid & 63;

  __shared__ __align__(16) half2_t h2s[H_ / 2];       // h_{t-1}, packed f16
  __shared__ __align__(16) half2_t x2s[4][F_ / 2];    // x ring, packed f16
  __shared__ float g_lds[G4];                         // activated gates

  // ---- prologue: this thread's W rows -> packed f16 registers
  half2_t whh[H_ / 2];   // 64 VGPRs
  half2_t wih[F_ / 2];   // 32 VGPRs
  {
    const float4* wr = (const float4*)(Whh + (size_t)tid * H_);
#pragma unroll
    for (int m = 0; m < H_ / 4; ++m) {
      float4 w = wr[m];
      whh[2 * m]     = pack2(w.x, w.y);
      whh[2 * m + 1] = pack2(w.z, w.w);
    }
    const float4* wr2 = (const float4*)(Wih + (size_t)tid * F_);
#pragma unroll
    for (int m = 0; m < F_ / 4; ++m) {
      float4 w = wr2[m];
      wih[2 * m]     = pack2(w.x, w.y);
      wih[2 * m + 1] = pack2(w.z, w.w);
    }
  }
  const float bias = bih[tid] + bhh[tid];

  // h0 = 0
  if (tid < H_ / 2) h2s[tid] = pack2(0.f, 0.f);

  // ---- x prefetch pipeline: wave 7, lanes 0..31; slot u%4 holds x[u]
  const bool   xloader = (tid >= 448) && (lane < 32);
  const float* xbase   = X + (size_t)b * T_ * F_;
  float2 xq0, xq1;
  if (xloader) {
    float2 a0 = ((const float2*)(xbase + 0 * F_))[lane];
    float2 a1 = ((const float2*)(xbase + 1 * F_))[lane];
    x2s[0][lane] = pack2(a0.x, a0.y);
    x2s[1][lane] = pack2(a1.x, a1.y);
    xq0 = ((const float2*)(xbase + 2 * F_))[lane];
    xq1 = ((const float2*)(xbase + 3 * F_))[lane];
  }

  float c_state = 0.f;
  float h_last  = 0.f;

  __syncthreads();

#pragma unroll 2
  for (int t = 0; t < T_; ++t) {
    // ---- gate preactivation: bias + Wih.x_t + Whh.h_{t-1}
    float a0 = bias, a1 = 0.f, a2 = 0.f, a3 = 0.f;
    const half2_t* xs = x2s[t & 3];
#pragma unroll
    for (int m = 0; m < F_ / 2; m += 4) {
      a0 = fdot2(wih[m + 0], xs[m + 0], a0);
      a1 = fdot2(wih[m + 1], xs[m + 1], a1);
      a2 = fdot2(wih[m + 2], xs[m + 2], a2);
      a3 = fdot2(wih[m + 3], xs[m + 3], a3);
    }
#pragma unroll
    for (int m = 0; m < H_ / 2; m += 4) {
      a0 = fdot2(whh[m + 0], h2s[m + 0], a0);
      a1 = fdot2(whh[m + 1], h2s[m + 1], a1);
      a2 = fdot2(whh[m + 2], h2s[m + 2], a2);
      a3 = fdot2(whh[m + 3], h2s[m + 3], a3);
    }
    float pre = (a0 + a1) + (a2 + a3);

    // ---- activation: waves 4,5 hold the g-gate rows (tanh), others sigmoid
    const int wv = tid >> 6;
    float act = (wv == 4 || wv == 5) ? fast_tanh(pre) : fast_sigmoid(pre);
    g_lds[tid] = act;

    // ---- prefetch: stage x[t+2] to LDS, issue load of x[t+4]
    if (xloader) {
      int nu = t + 4; nu = (nu < T_) ? nu : (T_ - 1);
      const float2* xrn = (const float2*)(xbase + (size_t)nu * F_);
      if ((t & 1) == 0) {          // static under unroll-2: no read of in-flight reg
        x2s[(t + 2) & 3][lane] = pack2(xq0.x, xq0.y);
        xq0 = xrn[lane];
      } else {
        x2s[(t + 2) & 3][lane] = pack2(xq1.x, xq1.y);
        xq1 = xrn[lane];
      }
    }

    __syncthreads();   // gates visible; h2s reads of this step done

    // ---- c/h update on threads 0..127
    if (tid < H_) {
      float ai = g_lds[tid];
      float af = g_lds[tid + H_];
      float ag = g_lds[tid + 2 * H_];
      float ao = g_lds[tid + 3 * H_];
      c_state = af * c_state + ai * ag;
      float hn = ao * fast_tanh(c_state);
      ((_Float16*)h2s)[tid] = (_Float16)hn;   // f16 h for next step's dot2
      h_last = hn;
    }
    __syncthreads();   // new h/x visible before next step
  }

  if (tid < H_) out[(size_t)b * H_ + tid] = h_last;
}

extern "C" void kernel_launch(void* const* d_in, const int* in_sizes, int n_in,
                              void* d_out, int out_size, void* d_ws, size_t ws_size,
                              hipStream_t stream) {
  const float* X   = (const float*)d_in[0];
  const float* Wih = (const float*)d_in[1];
  const float* Whh = (const float*)d_in[2];
  const float* bih = (const float*)d_in[3];
  const float* bhh = (const float*)d_in[4];
  float* out = (float*)d_out;

  lstm_seq_kernel<<<dim3(B_), dim3(G4), 0, stream>>>(X, Wih, Whh, bih, bhh, out);
}

// Round 2
// 2920.961 us; speedup vs baseline: 1.0861x; 1.0861x over previous
//
#include <hip/hip_runtime.h>

#define B_  128
#define T_  4096
#define F_  64
#define H_  128
#define NT  512
#define PART_STRIDE 516   // dwords per partial-slice row (516*4 % 16 == 0, %32 banks = 4)

typedef _Float16 half2_t __attribute__((ext_vector_type(2)));
typedef _Float16 half8_t __attribute__((ext_vector_type(8)));

#if __has_builtin(__builtin_amdgcn_fdot2)
__device__ __forceinline__ float fdot2(half2_t a, half2_t b, float c) {
  return __builtin_amdgcn_fdot2(a, b, c, false);
}
#else
__device__ __forceinline__ float fdot2(half2_t a, half2_t b, float c) {
  return c + (float)a[0] * (float)b[0] + (float)a[1] * (float)b[1];
}
#endif

__device__ __forceinline__ half2_t pack2(float a, float b) {
  half2_t r; r[0] = (_Float16)a; r[1] = (_Float16)b; return r;
}

// quad-broadcast lane (base|Q) -> all 4 lanes of the quad, via DPP (VALU pipe, no LDS)
template<int Q>
__device__ __forceinline__ float qbcast(float v) {
  return __int_as_float(__builtin_amdgcn_update_dpp(
      0, __float_as_int(v), Q * 0x55 /*quad_perm all->Q*/, 0xF, 0xF, true));
}

__device__ __forceinline__ float fast_tanh(float x) {
  // tanh(x) = 2/(1+2^(-2x*log2e)) - 1
  float e = __builtin_amdgcn_exp2f(x * -2.8853900817779268f);
  return 2.0f * __builtin_amdgcn_rcpf(1.0f + e) - 1.0f;
}

__global__ __launch_bounds__(512, 2) void lstm_ksplit_kernel(
    const float* __restrict__ X,    // [B, T, F]
    const float* __restrict__ Wih,  // [4H, F]
    const float* __restrict__ Whh,  // [4H, H]
    const float* __restrict__ bih,  // [4H]
    const float* __restrict__ bhh,  // [4H]
    float* __restrict__ out)        // [B, H]
{
  const int tid  = threadIdx.x;
  const int b    = blockIdx.x;
  const int lane = tid & 63;
  const int w    = tid >> 6;     // wave 0..7
  const int s    = w >> 1;       // k-slice 0..3  (k in [48s, 48s+48))
  const int hw   = w & 1;        // column half
  const int col  = 64 * hw + lane;   // writer-side column 0..127

  // k operand vector [h(128 f16) | x(64 f16)] = 192 halves = 96 half2, double-buffered
  __shared__ __align__(16) half2_t kbuf[2][96];
  __shared__ __align__(16) float   part[4][PART_STRIDE];

  // ---- prologue: this thread's 4 W-row slices (gates r*128+col, k-cols [48s,48s+48))
  half2_t Wr[4][24];   // 96 VGPRs
  const int k0 = 48 * s;
#pragma unroll
  for (int r = 0; r < 4; ++r) {
    const int g = r * 128 + col;
#pragma unroll
    for (int j = 0; j < 24; ++j) {
      const int k = k0 + 2 * j;
      float2 wv;
      if (k < 128) wv = *(const float2*)(Whh + (size_t)g * H_ + k);
      else         wv = *(const float2*)(Wih + (size_t)g * F_ + (k - 128));
      Wr[r][j] = pack2(wv.x, wv.y);
    }
  }
  float bias_r[4];
#pragma unroll
  for (int r = 0; r < 4; ++r) {
    const int g = r * 128 + col;
    bias_r[r] = (s == 0) ? (bih[g] + bhh[g]) : 0.0f;   // bias folded into slice-0 partials
  }

  // ---- reduce-side constants: thread tid owns gate (tid&3)*128 + (tid>>2)
  const int  rcol = tid >> 2;
  const bool is_g = ((tid & 3) == 2);
  const float AK1 = is_g ? -2.8853900817779268f : -1.4426950408889634f;
  const float AK2 = is_g ? 2.0f : 1.0f;
  const float AK3 = is_g ? -1.0f : 0.0f;

  // ---- init h0 = 0 (halves 0..127 of kbuf[0])
  if (tid < H_) ((_Float16*)&kbuf[0][0])[tid] = (_Float16)0.0f;

  // ---- x staging: wave 7, lanes 0..31; x region = half2 indices [64, 96)
  const bool   xloader = (w == 7) && (lane < 32);
  const float* xbase   = X + (size_t)b * T_ * F_;
  float2 xq0, xq1;
  if (xloader) {
    float2 a0 = ((const float2*)(xbase + 0 * F_))[lane];
    kbuf[0][64 + lane] = pack2(a0.x, a0.y);          // x[0] -> buf 0
    xq0 = ((const float2*)(xbase + 1 * F_))[lane];   // holds x[1]
    xq1 = ((const float2*)(xbase + 2 * F_))[lane];   // holds x[2]
  }

  float c_state = 0.0f;
  float h_last  = 0.0f;

  __syncthreads();

#pragma unroll 2
  for (int t = 0; t < T_; ++t) {
    const int buf = t & 1;

    // ---- dot phase: read this wave's 96B k-slice (6 x ds_read_b128, wave-uniform)
    union H8 { half8_t v8; half2_t h2[4]; };
    H8 kv[6];
    const half8_t* kp = (const half8_t*)&kbuf[buf][24 * s];
#pragma unroll
    for (int u = 0; u < 6; ++u) kv[u].v8 = kp[u];

    float acc0 = bias_r[0], acc1 = bias_r[1], acc2 = bias_r[2], acc3 = bias_r[3];
#pragma unroll
    for (int u = 0; u < 6; ++u) {
#pragma unroll
      for (int m = 0; m < 4; ++m) {
        const half2_t kk = kv[u].h2[m];
        const int j = u * 4 + m;
        acc0 = fdot2(Wr[0][j], kk, acc0);
        acc1 = fdot2(Wr[1][j], kk, acc1);
        acc2 = fdot2(Wr[2][j], kk, acc2);
        acc3 = fdot2(Wr[3][j], kk, acc3);
      }
    }
    // partial write: part[s][4*col + r]  (one ds_write_b128, bank-balanced)
    float4 pw; pw.x = acc0; pw.y = acc1; pw.z = acc2; pw.w = acc3;
    *(float4*)&part[s][4 * col] = pw;

    __syncthreads();   // B1: partials visible

    // ---- reduce + activation (thread tid <-> gate (tid&3)*128 + rcol)
    float pre = (part[0][tid] + part[1][tid]) + (part[2][tid] + part[3][tid]);
    float e   = __builtin_amdgcn_exp2f(pre * AK1);
    float act = AK2 * __builtin_amdgcn_rcpf(1.0f + e) + AK3;  // sigmoid, or tanh for g

    // quad gather: lanes 4c..4c+3 hold i,f,g,o of column rcol
    float ai = qbcast<0>(act);
    float af = qbcast<1>(act);
    float ag = qbcast<2>(act);
    float ao = qbcast<3>(act);

    c_state = af * c_state + ai * ag;
    float hn = ao * fast_tanh(c_state);
    h_last = hn;

    // h feedback -> next k-buffer (f16), one value per column
    if ((tid & 3) == 0)
      ((_Float16*)&kbuf[buf ^ 1][0])[rcol] = (_Float16)hn;

    // x[t+1] staging + prefetch x[t+3]
    if (xloader) {
      int nu = t + 3; nu = (nu < T_) ? nu : (T_ - 1);
      const float2* xrn = (const float2*)(xbase + (size_t)nu * F_);
      if ((t & 1) == 0) {            // static under unroll-2
        kbuf[buf ^ 1][64 + lane] = pack2(xq0.x, xq0.y);   // x[t+1]
        xq0 = xrn[lane];
      } else {
        kbuf[buf ^ 1][64 + lane] = pack2(xq1.x, xq1.y);
        xq1 = xrn[lane];
      }
    }

    __syncthreads();   // B2: next h/x visible; part safe to rewrite
  }

  if ((tid & 3) == 0) out[(size_t)b * H_ + rcol] = h_last;
}

extern "C" void kernel_launch(void* const* d_in, const int* in_sizes, int n_in,
                              void* d_out, int out_size, void* d_ws, size_t ws_size,
                              hipStream_t stream) {
  const float* X   = (const float*)d_in[0];
  const float* Wih = (const float*)d_in[1];
  const float* Whh = (const float*)d_in[2];
  const float* bih = (const float*)d_in[3];
  const float* bhh = (const float*)d_in[4];
  float* out = (float*)d_out;

  lstm_ksplit_kernel<<<dim3(B_), dim3(NT), 0, stream>>>(X, Wih, Whh, bih, bhh, out);
}